// Round 6
// baseline (227.066 us; speedup 1.0000x reference)
//
#include <hip/hip_runtime.h>
#include <math.h>

// DenseGATv2Layer: N=4096, IN=128, HEADS=4, OUT_DIM=64.
// R5: R3 post-mortem — aggr still latency-bound (MfmaUtil 6.7, VALUBusy 36,
// Occ 34.6 = 16 waves/CU). Fixes:
//  (1) aggr: M=32, 512-thr blocks, grid = 128 itiles x 8 jq = 1024 blocks ->
//      4 blocks/CU x 8 waves = 32 waves/CU; __launch_bounds__(512,8) caps
//      VGPR at 64 so they actually fit. Wave = (head, mg): one 16-row A-frag.
//  (2) explicit prefetch of next chunk's (mask, sjs) - the chunk-start
//      serial dependency.
//  (3) detect_fmt fused into pack_mask (every block re-derives the flag from
//      the first 4KB; L2 broadcast) -> one fewer dispatch (~70us of the 187
//      was unaccounted = per-dispatch overhead).
// jsplit=8 partial path hardcoded (R3 proved ws >= 38MB); atomic fallback kept.

#define N 4096
#define IN_DIM 128
#define HEADS 4
#define OUT_DIM 64
#define HD 256
#define NEG_INF -9.0e15f
#define LOG2E 1.4426950408889634f

typedef _Float16 f16x8 __attribute__((ext_vector_type(8)));
typedef __fp16 fp16x2 __attribute__((ext_vector_type(2)));
typedef float f32x4 __attribute__((ext_vector_type(4)));

union F16x8u { fp16x2 h2[4]; f16x8 v; };

// ws layout (bytes)
#define WS_HC_OFF    0u          // _Float16 h_c16[256][4096]   (2 MB)
#define WS_SSRC_OFF  2097152u    // float s_src[N][4]   (scaled by log2e)
#define WS_SDST_OFF  2162688u    // float s_dst[N][4]   (scaled)
#define WS_SDT_OFF   2228224u    // float s_dst_t[4][N] (scaled)
#define WS_L2L_OFF   2293760u    // float log2l[N][4]
#define WS_U_OFF     2359296u    // float U[N][4]
#define WS_BITS_OFF  2424832u    // uint bits[N][128]           (2 MB)
#define WS_PART_OFF  4718592u    // float partial[8][N][256]    (32 MB)
#define WS_NEEDED    (4718592u + 33554432u)

__device__ __forceinline__ float f4get(float4 v, int h) {
  return h == 0 ? v.x : h == 1 ? v.y : h == 2 ? v.z : v.w;
}
__device__ __forceinline__ float lrelu(float v) { return fmaxf(v, 0.2f * v); }

// ---------------- K1: pack mask to bits (format detect fused) ----------------
__device__ __forceinline__ unsigned pack_bytes(unsigned v) {
  return (v & 1u) | ((v >> 7) & 2u) | ((v >> 14) & 4u) | ((v >> 21) & 8u);
}

__global__ __launch_bounds__(256) void pack_mask_k(const void* __restrict__ mraw,
                                                   unsigned* __restrict__ bits) {
  // detect: scan first 1024 words (4KB, L2-broadcast across blocks).
  // byte-bool data: no word has a byte >1 (!bad) and some word >1 (g).
  // int32 0/1: words are 0/1 -> g=0. float 1.0f: 0x3F800000 -> bad.
  __shared__ int s_flag;
  if (threadIdx.x == 0) s_flag = 0;
  __syncthreads();
  const unsigned* mw = (const unsigned*)mraw;
  int bad = 0, g = 0;
  for (int i = threadIdx.x; i < 1024; i += 256) {
    unsigned v = mw[i];
    if (v & 0xFEFEFEFEu) bad = 1;
    if (v > 1u) g = 1;
  }
  if (bad || g) atomicOr(&s_flag, (bad ? 1 : 0) | (g ? 2 : 0));
  __syncthreads();
  const bool byte_fmt = ((s_flag & 1) == 0) && ((s_flag & 2) != 0);

  int w = blockIdx.x * blockDim.x + threadIdx.x;  // word idx, N*N/32 total
  unsigned ob = 0u;
  if (byte_fmt) {
    const uint4* p = (const uint4*)((const unsigned char*)mraw + (size_t)w * 32u);
    uint4 a = p[0], b = p[1];
    ob  =  pack_bytes(a.x)        | (pack_bytes(a.y) << 4)  | (pack_bytes(a.z) << 8)  | (pack_bytes(a.w) << 12);
    ob |= (pack_bytes(b.x) << 16) | (pack_bytes(b.y) << 20) | (pack_bytes(b.z) << 24) | (pack_bytes(b.w) << 28);
  } else {
    const uint4* p = (const uint4*)((const unsigned*)mraw + (size_t)w * 32u);
#pragma unroll
    for (int k = 0; k < 8; ++k) {
      uint4 v = p[k];
      ob |= (v.x ? 1u : 0u) << (4 * k);
      ob |= (v.y ? 1u : 0u) << (4 * k + 1);
      ob |= (v.z ? 1u : 0u) << (4 * k + 2);
      ob |= (v.w ? 1u : 0u) << (4 * k + 3);
    }
  }
  bits[w] = ob;
}

// ---------------- K2: h = x@W; h_c16 fp16 transposed; scaled s vectors ----------------
__global__ __launch_bounds__(256) void compute_h(const float* __restrict__ x,
                                                 const float* __restrict__ W,
                                                 const float* __restrict__ a_src,
                                                 const float* __restrict__ a_dst,
                                                 _Float16* __restrict__ h_c16,
                                                 float* __restrict__ s_src,
                                                 float* __restrict__ s_dst,
                                                 float* __restrict__ s_dst_t) {
  const int i0 = blockIdx.x * 8;
  const int c = threadIdx.x;

  float acc[8];
#pragma unroll
  for (int r = 0; r < 8; ++r) acc[r] = 0.f;

  for (int kk = 0; kk < IN_DIM / 4; ++kk) {
    const int k = kk * 4;
    float w0 = W[(size_t)(k + 0) * HD + c];
    float w1 = W[(size_t)(k + 1) * HD + c];
    float w2 = W[(size_t)(k + 2) * HD + c];
    float w3 = W[(size_t)(k + 3) * HD + c];
#pragma unroll
    for (int r = 0; r < 8; ++r) {
      float4 xv = *(const float4*)(x + (size_t)(i0 + r) * IN_DIM + k);  // uniform -> s_load
      acc[r] = fmaf(xv.x, w0, fmaf(xv.y, w1, fmaf(xv.z, w2, fmaf(xv.w, w3, acc[r]))));
    }
  }

  f16x8 lo;
#pragma unroll
  for (int r = 0; r < 8; ++r) lo[r] = (_Float16)acc[r];
  *(f16x8*)(h_c16 + (size_t)c * N + i0) = lo;

  const int hw = c >> 6, lane = c & 63;
  const float as = a_src[lane], ad = a_dst[lane];
#pragma unroll
  for (int r = 0; r < 8; ++r) {
    float vs = acc[r] * as, vd = acc[r] * ad;
#pragma unroll
    for (int off = 1; off < 64; off <<= 1) {
      vs += __shfl_xor(vs, off);
      vd += __shfl_xor(vd, off);
    }
    if (lane == 0) {
      s_src[(size_t)(i0 + r) * HEADS + hw] = vs * LOG2E;
      s_dst[(size_t)(i0 + r) * HEADS + hw] = vd * LOG2E;
      s_dst_t[(size_t)hw * N + (i0 + r)] = vd * LOG2E;
    }
  }
}

// ---------------- K3: per-row softmax denom (single pass, exp2 domain) ----------------
__global__ __launch_bounds__(256) void gat_scores(const float* __restrict__ s_src,
                                                  const float* __restrict__ s_dst,
                                                  const unsigned* __restrict__ bits,
                                                  float* __restrict__ log2l_ws,
                                                  float* __restrict__ U_ws) {
  const int tid = threadIdx.x;
  const int wave = tid >> 6;
  const int lane = tid & 63;
  const int row = blockIdx.x * 4 + wave;

  const float4* sd4 = (const float4*)s_dst;
  const unsigned long long* mb64 = (const unsigned long long*)bits + (size_t)row * 64;

  float4 siv = ((const float4*)s_src)[row];
  float si[4] = {siv.x, siv.y, siv.z, siv.w};
  float l[4] = {0.f, 0.f, 0.f, 0.f};

  for (int jb = 0; jb < N / 256; ++jb) {
    float4 sj[4];
    unsigned long long w[4];
#pragma unroll
    for (int u = 0; u < 4; ++u) {
      sj[u] = sd4[jb * 256 + u * 64 + lane];
      w[u] = mb64[jb * 4 + u];
    }
#pragma unroll
    for (int u = 0; u < 4; ++u) {
      bool e = (w[u] >> lane) & 1ull;
#pragma unroll
      for (int h = 0; h < 4; ++h) {
        float ev = __builtin_amdgcn_exp2f(lrelu(si[h] + f4get(sj[u], h)));
        l[h] += e ? ev : 0.f;
      }
    }
  }
#pragma unroll
  for (int off = 1; off < 64; off <<= 1)
#pragma unroll
    for (int h = 0; h < 4; ++h) l[h] += __shfl_xor(l[h], off);

  if (lane == 0) {
#pragma unroll
    for (int h = 0; h < 4; ++h) {
      bool empty = (l[h] == 0.f);
      log2l_ws[(size_t)row * HEADS + h] = empty ? 12.0f : __log2f(l[h]);
      U_ws[(size_t)row * HEADS + h] = empty ? 0.f : -1.0e38f;
    }
  }
}

// ---------------- K4: MFMA aggregation, M=32, 32 waves/CU ----------------
// grid = 128 itiles x 8 jq = 1024 blocks x 512 thr (8 waves). wave = (head,
// mg): one 16-row M-tile. jq = bid&7 keeps each XCD on one 256KB h-slice.
// Per 32-j chunk: A-frag synthesized in regs (p = exp2(x + nl)), 4 B-frags,
// 4 MFMAs. Next chunk's (mask, sjs) prefetched during current synth+MFMA.
__global__ __launch_bounds__(512, 8) void gat_aggr(const _Float16* __restrict__ h_c16,
                                                   const float* __restrict__ s_src,
                                                   const float* __restrict__ s_dst_t,
                                                   const float* __restrict__ log2l_ws,
                                                   const float* __restrict__ U_ws,
                                                   const unsigned* __restrict__ bits,
                                                   float* __restrict__ dst,
                                                   int atomic_mode) {
  const int tid = threadIdx.x;
  const int wave = tid >> 6;
  const int lane = tid & 63;
  const int head = wave & 3;
  const int mg = wave >> 2;
  const int m15 = lane & 15;
  const int quad = lane >> 4;
  const int jq = blockIdx.x & 7;
  const int i0 = (blockIdx.x >> 3) * 32;
  const int rA = i0 + mg * 16 + m15;

  const float siA = s_src[(size_t)rA * HEADS + head];
  const float nlA = -log2l_ws[(size_t)rA * HEADS + head];
  const float UA = U_ws[(size_t)rA * HEADS + head];

  const unsigned* mrow = bits + (size_t)rA * 128 + jq * 16;            // 16 chunk words
  const float* sjb = s_dst_t + (size_t)head * N + jq * 512 + quad * 8;
  const _Float16* hbase = h_c16 + ((size_t)(head * 64 + m15)) * N + jq * 512 + quad * 8;

  f32x4 acc0 = {0.f, 0.f, 0.f, 0.f}, acc1 = acc0, acc2 = acc0, acc3 = acc0;

  const int shq = quad * 8;

  unsigned wcur = mrow[0];
  float4 sa = *(const float4*)(sjb);
  float4 sb = *(const float4*)(sjb + 4);

  for (int c = 0; c < 16; ++c) {
    const int j0 = c * 32;
    // B-frag loads for this chunk (issue early; consumed after synthesis)
    const f16x8 b0 = *(const f16x8*)(hbase + j0);
    const f16x8 b1 = *(const f16x8*)(hbase + (size_t)16 * N + j0);
    const f16x8 b2 = *(const f16x8*)(hbase + (size_t)32 * N + j0);
    const f16x8 b3 = *(const f16x8*)(hbase + (size_t)48 * N + j0);

    // prefetch next chunk's serializers
    const int cn = c < 15 ? c + 1 : 15;
    unsigned wnext = mrow[cn];
    float4 na = *(const float4*)(sjb + cn * 32);
    float4 nb = *(const float4*)(sjb + cn * 32 + 4);

    const unsigned wA = wcur >> shq;
    const float sjs[8] = {sa.x, sa.y, sa.z, sa.w, sb.x, sb.y, sb.z, sb.w};

    F16x8u uA;
#pragma unroll
    for (int t2 = 0; t2 < 4; ++t2) {
      float pA[2];
#pragma unroll
      for (int q = 0; q < 2; ++q) {
        const int t = t2 * 2 + q;
        float vA = lrelu(siA + sjs[t]);
        float xA = ((wA >> t) & 1u) ? vA : UA;
        pA[q] = __builtin_amdgcn_exp2f(xA + nlA);
      }
      uA.h2[t2] = __builtin_amdgcn_cvt_pkrtz(pA[0], pA[1]);
    }

    acc0 = __builtin_amdgcn_mfma_f32_16x16x32_f16(uA.v, b0, acc0, 0, 0, 0);
    acc1 = __builtin_amdgcn_mfma_f32_16x16x32_f16(uA.v, b1, acc1, 0, 0, 0);
    acc2 = __builtin_amdgcn_mfma_f32_16x16x32_f16(uA.v, b2, acc2, 0, 0, 0);
    acc3 = __builtin_amdgcn_mfma_f32_16x16x32_f16(uA.v, b3, acc3, 0, 0, 0);

    wcur = wnext; sa = na; sb = nb;
  }

  // D layout: col = lane&15 (d in tile), row = quad*4 + reg (i in 16-tile)
  const int colb = head * 64 + m15;
  if (atomic_mode) {
    float* oA = dst + (size_t)(i0 + mg * 16 + quad * 4) * HD + colb;
#pragma unroll
    for (int reg = 0; reg < 4; ++reg) {
      atomicAdd(oA + (size_t)reg * HD + 0,  acc0[reg]);
      atomicAdd(oA + (size_t)reg * HD + 16, acc1[reg]);
      atomicAdd(oA + (size_t)reg * HD + 32, acc2[reg]);
      atomicAdd(oA + (size_t)reg * HD + 48, acc3[reg]);
    }
  } else {
    float* oA = dst + (size_t)jq * (N * HD) + (size_t)(i0 + mg * 16 + quad * 4) * HD + colb;
#pragma unroll
    for (int reg = 0; reg < 4; ++reg) {
      oA[(size_t)reg * HD + 0]  = acc0[reg];
      oA[(size_t)reg * HD + 16] = acc1[reg];
      oA[(size_t)reg * HD + 32] = acc2[reg];
      oA[(size_t)reg * HD + 48] = acc3[reg];
    }
  }
}

// ---------------- K5: combine 8 partial slices ----------------
__global__ __launch_bounds__(256) void reduce_part(const float4* __restrict__ part,
                                                   float4* __restrict__ out) {
  const size_t idx = (size_t)blockIdx.x * 256 + threadIdx.x;
  const size_t S = (size_t)N * HD / 4;
  float4 o = part[idx];
#pragma unroll
  for (int k = 1; k < 8; ++k) {
    float4 a = part[idx + (size_t)k * S];
    o.x += a.x; o.y += a.y; o.z += a.z; o.w += a.w;
  }
  out[idx] = o;
}

extern "C" void kernel_launch(void* const* d_in, const int* in_sizes, int n_in,
                              void* d_out, int out_size, void* d_ws, size_t ws_size,
                              hipStream_t stream) {
  (void)in_sizes; (void)n_in;
  const float* x = (const float*)d_in[0];
  const void* mask = d_in[1];
  const float* W = (const float*)d_in[2];
  const float* a_src = (const float*)d_in[3];
  const float* a_dst = (const float*)d_in[4];
  float* out = (float*)d_out;

  char* ws = (char*)d_ws;
  _Float16* h_c16 = (_Float16*)(ws + WS_HC_OFF);
  float* s_src = (float*)(ws + WS_SSRC_OFF);
  float* s_dst = (float*)(ws + WS_SDST_OFF);
  float* s_dst_t = (float*)(ws + WS_SDT_OFF);
  float* log2l_ws = (float*)(ws + WS_L2L_OFF);
  float* U_ws = (float*)(ws + WS_U_OFF);
  unsigned* bits = (unsigned*)(ws + WS_BITS_OFF);
  float* partial = (float*)(ws + WS_PART_OFF);

  pack_mask_k<<<(N * N / 32) / 256, 256, 0, stream>>>(mask, bits);
  compute_h<<<N / 8, 256, 0, stream>>>(x, W, a_src, a_dst, h_c16, s_src, s_dst, s_dst_t);
  gat_scores<<<N / 4, 256, 0, stream>>>(s_src, s_dst, bits, log2l_ws, U_ws);

  if (ws_size >= (size_t)WS_NEEDED) {
    gat_aggr<<<(N / 32) * 8, 512, 0, stream>>>(h_c16, s_src, s_dst_t, log2l_ws, U_ws,
                                               bits, partial, 0);
    reduce_part<<<(N * HD / 4) / 256, 256, 0, stream>>>((const float4*)partial, (float4*)out);
  } else {
    (void)hipMemsetAsync(out, 0, (size_t)out_size * sizeof(float), stream);
    gat_aggr<<<(N / 32) * 8, 512, 0, stream>>>(h_c16, s_src, s_dst_t, log2l_ws, U_ws,
                                               bits, out, 1);
  }
}

// Round 7
// 173.952 us; speedup vs baseline: 1.3053x; 1.3053x over previous
//
#include <hip/hip_runtime.h>
#include <math.h>

// DenseGATv2Layer: N=4096, IN=128, HEADS=4, OUT_DIM=64.
// R6: R5 post-mortem — aggr time scales with B-frag LOAD INSTRUCTION count
// (~100 cyc/CU each: 16-row x 8KB-stride scatter = 16 separate 64B requests
// per instruction). Occupancy was NOT the limit (R5: occ 61%, 2x slower).
// Fixes:
//  (1) compute_h stores h DIRECTLY in MFMA B-fragment-linear layout hb:
//      unit=(head,chunk,ntile) -> 512 f16; elem (lane=quad*16+m15, t) =
//      h[j=chunk*32+quad*8+t][d=head*64+nt*16+m15]. Aggr B-load = one
//      contiguous 1KB wave load. No separate repack kernel needed.
//  (2) pack_mask also writes transposed bits_t[(it*128+jc)*64+row] so the
//      aggr mask load is a coalesced 64B run.
//  (3) aggr back to the proven M=64 shape (512 blk x 8 waves, 2 row-groups
//      per wave, 8 MFMAs per 4 B-loads), jsplit=8 partials + reduce.

#define N 4096
#define IN_DIM 128
#define HEADS 4
#define OUT_DIM 64
#define HD 256
#define LOG2E 1.4426950408889634f

typedef _Float16 f16x8 __attribute__((ext_vector_type(8)));
typedef __fp16 fp16x2 __attribute__((ext_vector_type(2)));
typedef float f32x4 __attribute__((ext_vector_type(4)));

union F16x8u { fp16x2 h2[4]; f16x8 v; };

// ws layout (bytes)
#define WS_HB_OFF    0u          // _Float16 hb[2048][512]      (2 MB) frag-linear
#define WS_SSRC_OFF  2097152u    // float s_src[N][4]   (scaled by log2e)
#define WS_SDST_OFF  2162688u    // float s_dst[N][4]   (scaled)
#define WS_SDT_OFF   2228224u    // float s_dst_t[4][N] (scaled)
#define WS_L2L_OFF   2293760u    // float log2l[N][4]
#define WS_U_OFF     2359296u    // float U[N][4]
#define WS_BITS_OFF  2424832u    // uint bits[N][128]           (2 MB) row-major
#define WS_BITT_OFF  4521984u    // uint bits_t[64][128][64]    (2 MB) aggr layout
#define WS_PART_OFF  6619136u    // float partial[8][N][256]    (32 MB)
#define WS_NEEDED    (6619136u + 33554432u)

__device__ __forceinline__ float f4get(float4 v, int h) {
  return h == 0 ? v.x : h == 1 ? v.y : h == 2 ? v.z : v.w;
}
__device__ __forceinline__ float lrelu(float v) { return fmaxf(v, 0.2f * v); }

// ---------------- K1: pack mask to bits + bits_t (format detect fused) ----------------
__device__ __forceinline__ unsigned pack_bytes(unsigned v) {
  return (v & 1u) | ((v >> 7) & 2u) | ((v >> 14) & 4u) | ((v >> 21) & 8u);
}

__global__ __launch_bounds__(256) void pack_mask_k(const void* __restrict__ mraw,
                                                   unsigned* __restrict__ bits,
                                                   unsigned* __restrict__ bits_t) {
  // detect from first 4KB (L2-broadcast): byte-bool iff no byte>1 and some word>1.
  __shared__ int s_flag;
  if (threadIdx.x == 0) s_flag = 0;
  __syncthreads();
  const unsigned* mw = (const unsigned*)mraw;
  int bad = 0, g = 0;
  for (int i = threadIdx.x; i < 1024; i += 256) {
    unsigned v = mw[i];
    if (v & 0xFEFEFEFEu) bad = 1;
    if (v > 1u) g = 1;
  }
  if (bad || g) atomicOr(&s_flag, (bad ? 1 : 0) | (g ? 2 : 0));
  __syncthreads();
  const bool byte_fmt = ((s_flag & 1) == 0) && ((s_flag & 2) != 0);

  int w = blockIdx.x * blockDim.x + threadIdx.x;  // word idx, N*N/32 total
  unsigned ob = 0u;
  if (byte_fmt) {
    const uint4* p = (const uint4*)((const unsigned char*)mraw + (size_t)w * 32u);
    uint4 a = p[0], b = p[1];
    ob  =  pack_bytes(a.x)        | (pack_bytes(a.y) << 4)  | (pack_bytes(a.z) << 8)  | (pack_bytes(a.w) << 12);
    ob |= (pack_bytes(b.x) << 16) | (pack_bytes(b.y) << 20) | (pack_bytes(b.z) << 24) | (pack_bytes(b.w) << 28);
  } else {
    const uint4* p = (const uint4*)((const unsigned*)mraw + (size_t)w * 32u);
#pragma unroll
    for (int k = 0; k < 8; ++k) {
      uint4 v = p[k];
      ob |= (v.x ? 1u : 0u) << (4 * k);
      ob |= (v.y ? 1u : 0u) << (4 * k + 1);
      ob |= (v.z ? 1u : 0u) << (4 * k + 2);
      ob |= (v.w ? 1u : 0u) << (4 * k + 3);
    }
  }
  bits[w] = ob;
  const int row = w >> 7, jc = w & 127;
  bits_t[((size_t)(row >> 6) * 128 + jc) * 64 + (row & 63)] = ob;
}

// ---------------- K2: h = x@W -> hb (frag-linear fp16); scaled s vectors ----------------
// 512 blocks x 256 thr; block = 8 rows (j's). thread c = head*64+nt*16+m15.
// The 8 j-values of thread c form one (lane',t=0..7) run of fragment unit
// (head, chunk=i0>>5, nt) at lane' = ((i0&31)>>3)*16 + m15 -> single f16x8 store.
__global__ __launch_bounds__(256) void compute_h(const float* __restrict__ x,
                                                 const float* __restrict__ W,
                                                 const float* __restrict__ a_src,
                                                 const float* __restrict__ a_dst,
                                                 _Float16* __restrict__ hb,
                                                 float* __restrict__ s_src,
                                                 float* __restrict__ s_dst,
                                                 float* __restrict__ s_dst_t) {
  const int i0 = blockIdx.x * 8;
  const int c = threadIdx.x;

  float acc[8];
#pragma unroll
  for (int r = 0; r < 8; ++r) acc[r] = 0.f;

  for (int kk = 0; kk < IN_DIM / 4; ++kk) {
    const int k = kk * 4;
    float w0 = W[(size_t)(k + 0) * HD + c];
    float w1 = W[(size_t)(k + 1) * HD + c];
    float w2 = W[(size_t)(k + 2) * HD + c];
    float w3 = W[(size_t)(k + 3) * HD + c];
#pragma unroll
    for (int r = 0; r < 8; ++r) {
      float4 xv = *(const float4*)(x + (size_t)(i0 + r) * IN_DIM + k);  // uniform -> s_load
      acc[r] = fmaf(xv.x, w0, fmaf(xv.y, w1, fmaf(xv.z, w2, fmaf(xv.w, w3, acc[r]))));
    }
  }

  // frag-linear store
  {
    const int head = c >> 6, nt = (c >> 4) & 3, m15 = c & 15;
    const int unit = (head * 128 + (i0 >> 5)) * 4 + nt;
    const int lanep = ((i0 & 31) >> 3) * 16 + m15;
    f16x8 v;
#pragma unroll
    for (int r = 0; r < 8; ++r) v[r] = (_Float16)acc[r];
    *(f16x8*)(hb + (size_t)unit * 512 + lanep * 8) = v;
  }

  const int hw = c >> 6, lane = c & 63;
  const float as = a_src[lane], ad = a_dst[lane];
#pragma unroll
  for (int r = 0; r < 8; ++r) {
    float vs = acc[r] * as, vd = acc[r] * ad;
#pragma unroll
    for (int off = 1; off < 64; off <<= 1) {
      vs += __shfl_xor(vs, off);
      vd += __shfl_xor(vd, off);
    }
    if (lane == 0) {
      s_src[(size_t)(i0 + r) * HEADS + hw] = vs * LOG2E;
      s_dst[(size_t)(i0 + r) * HEADS + hw] = vd * LOG2E;
      s_dst_t[(size_t)hw * N + (i0 + r)] = vd * LOG2E;
    }
  }
}

// ---------------- K3: per-row softmax denom (single pass, exp2 domain) ----------------
__global__ __launch_bounds__(256) void gat_scores(const float* __restrict__ s_src,
                                                  const float* __restrict__ s_dst,
                                                  const unsigned* __restrict__ bits,
                                                  float* __restrict__ log2l_ws,
                                                  float* __restrict__ U_ws) {
  const int tid = threadIdx.x;
  const int wave = tid >> 6;
  const int lane = tid & 63;
  const int row = blockIdx.x * 4 + wave;

  const float4* sd4 = (const float4*)s_dst;
  const unsigned long long* mb64 = (const unsigned long long*)bits + (size_t)row * 64;

  float4 siv = ((const float4*)s_src)[row];
  float si[4] = {siv.x, siv.y, siv.z, siv.w};
  float l[4] = {0.f, 0.f, 0.f, 0.f};

  for (int jb = 0; jb < N / 256; ++jb) {
    float4 sj[4];
    unsigned long long w[4];
#pragma unroll
    for (int u = 0; u < 4; ++u) {
      sj[u] = sd4[jb * 256 + u * 64 + lane];
      w[u] = mb64[jb * 4 + u];
    }
#pragma unroll
    for (int u = 0; u < 4; ++u) {
      bool e = (w[u] >> lane) & 1ull;
#pragma unroll
      for (int h = 0; h < 4; ++h) {
        float ev = __builtin_amdgcn_exp2f(lrelu(si[h] + f4get(sj[u], h)));
        l[h] += e ? ev : 0.f;
      }
    }
  }
#pragma unroll
  for (int off = 1; off < 64; off <<= 1)
#pragma unroll
    for (int h = 0; h < 4; ++h) l[h] += __shfl_xor(l[h], off);

  if (lane == 0) {
#pragma unroll
    for (int h = 0; h < 4; ++h) {
      bool empty = (l[h] == 0.f);
      log2l_ws[(size_t)row * HEADS + h] = empty ? 12.0f : __log2f(l[h]);
      U_ws[(size_t)row * HEADS + h] = empty ? 0.f : -1.0e38f;
    }
  }
}

// ---------------- K4: MFMA aggregation, M=64, contiguous frag loads ----------------
// grid = 64 itiles x 8 jq = 512 blocks x 512 thr (8 waves). wave = (head, mg):
// rows rA = i0+mg*32+m15, rB = rA+16. Per 32-j chunk: 2 A-frags synthesized in
// regs, 4 B-frags as CONTIGUOUS 1KB wave-loads from hb, coalesced mask words
// from bits_t, 8 MFMAs.
__global__ __launch_bounds__(512, 4) void gat_aggr(const _Float16* __restrict__ hb,
                                                   const float* __restrict__ s_src,
                                                   const float* __restrict__ s_dst_t,
                                                   const float* __restrict__ log2l_ws,
                                                   const float* __restrict__ U_ws,
                                                   const unsigned* __restrict__ bits_t,
                                                   float* __restrict__ dst,
                                                   int atomic_mode) {
  const int tid = threadIdx.x;
  const int wave = tid >> 6;
  const int lane = tid & 63;
  const int head = wave & 3;
  const int mg = wave >> 2;
  const int m15 = lane & 15;
  const int quad = lane >> 4;
  const int jq = blockIdx.x & 7;
  const int it = blockIdx.x >> 3;
  const int i0 = it * 64;
  const int rA = i0 + mg * 32 + m15;
  const int rB = rA + 16;

  const float siA = s_src[(size_t)rA * HEADS + head];
  const float siB = s_src[(size_t)rB * HEADS + head];
  const float nlA = -log2l_ws[(size_t)rA * HEADS + head];
  const float nlB = -log2l_ws[(size_t)rB * HEADS + head];
  const float UA = U_ws[(size_t)rA * HEADS + head];
  const float UB = U_ws[(size_t)rB * HEADS + head];

  // mask: bits_t[(it*128 + jc)*64 + row-in-tile]; per chunk a 64B coalesced run
  const unsigned* mt = bits_t + ((size_t)it * 128 + jq * 16) * 64 + mg * 32 + m15;
  const float* sjb = s_dst_t + (size_t)head * N + jq * 512 + quad * 8;
  // B-frags: hb + unit*512 + lane*8, unit = (head*128 + jc)*4 + nt
  const _Float16* hbp = hb + ((size_t)(head * 128 + jq * 16) * 4) * 512 + lane * 8;

  f32x4 accA0 = {0.f, 0.f, 0.f, 0.f}, accA1 = accA0, accA2 = accA0, accA3 = accA0;
  f32x4 accB0 = accA0, accB1 = accA0, accB2 = accA0, accB3 = accA0;

  const int shq = quad * 8;

  for (int c = 0; c < 16; ++c) {
    const unsigned mwA = mt[c * 64];
    const unsigned mwB = mt[c * 64 + 16];
    const float4 sa = *(const float4*)(sjb + c * 32);
    const float4 sb = *(const float4*)(sjb + c * 32 + 4);

    const f16x8 b0 = *(const f16x8*)(hbp + (size_t)(c * 4 + 0) * 512);
    const f16x8 b1 = *(const f16x8*)(hbp + (size_t)(c * 4 + 1) * 512);
    const f16x8 b2 = *(const f16x8*)(hbp + (size_t)(c * 4 + 2) * 512);
    const f16x8 b3 = *(const f16x8*)(hbp + (size_t)(c * 4 + 3) * 512);

    const unsigned wA = mwA >> shq;
    const unsigned wB = mwB >> shq;
    const float sjs[8] = {sa.x, sa.y, sa.z, sa.w, sb.x, sb.y, sb.z, sb.w};

    F16x8u uA, uB;
#pragma unroll
    for (int t2 = 0; t2 < 4; ++t2) {
      float pA[2], pB[2];
#pragma unroll
      for (int q = 0; q < 2; ++q) {
        const int t = t2 * 2 + q;
        const float sj = sjs[t];
        float vA = lrelu(siA + sj);
        float vB = lrelu(siB + sj);
        float xA = ((wA >> t) & 1u) ? vA : UA;
        float xB = ((wB >> t) & 1u) ? vB : UB;
        pA[q] = __builtin_amdgcn_exp2f(xA + nlA);
        pB[q] = __builtin_amdgcn_exp2f(xB + nlB);
      }
      uA.h2[t2] = __builtin_amdgcn_cvt_pkrtz(pA[0], pA[1]);
      uB.h2[t2] = __builtin_amdgcn_cvt_pkrtz(pB[0], pB[1]);
    }

    accA0 = __builtin_amdgcn_mfma_f32_16x16x32_f16(uA.v, b0, accA0, 0, 0, 0);
    accA1 = __builtin_amdgcn_mfma_f32_16x16x32_f16(uA.v, b1, accA1, 0, 0, 0);
    accA2 = __builtin_amdgcn_mfma_f32_16x16x32_f16(uA.v, b2, accA2, 0, 0, 0);
    accA3 = __builtin_amdgcn_mfma_f32_16x16x32_f16(uA.v, b3, accA3, 0, 0, 0);
    accB0 = __builtin_amdgcn_mfma_f32_16x16x32_f16(uB.v, b0, accB0, 0, 0, 0);
    accB1 = __builtin_amdgcn_mfma_f32_16x16x32_f16(uB.v, b1, accB1, 0, 0, 0);
    accB2 = __builtin_amdgcn_mfma_f32_16x16x32_f16(uB.v, b2, accB2, 0, 0, 0);
    accB3 = __builtin_amdgcn_mfma_f32_16x16x32_f16(uB.v, b3, accB3, 0, 0, 0);
  }

  // D layout: col = m15 (d in ntile), row = quad*4 + reg.
  const int colb = head * 64 + m15;
  if (atomic_mode) {
    float* oA = dst + (size_t)(i0 + mg * 32 + quad * 4) * HD + colb;
    float* oB = oA + (size_t)16 * HD;
#pragma unroll
    for (int reg = 0; reg < 4; ++reg) {
      atomicAdd(oA + (size_t)reg * HD + 0,  accA0[reg]);
      atomicAdd(oA + (size_t)reg * HD + 16, accA1[reg]);
      atomicAdd(oA + (size_t)reg * HD + 32, accA2[reg]);
      atomicAdd(oA + (size_t)reg * HD + 48, accA3[reg]);
      atomicAdd(oB + (size_t)reg * HD + 0,  accB0[reg]);
      atomicAdd(oB + (size_t)reg * HD + 16, accB1[reg]);
      atomicAdd(oB + (size_t)reg * HD + 32, accB2[reg]);
      atomicAdd(oB + (size_t)reg * HD + 48, accB3[reg]);
    }
  } else {
    float* oA = dst + (size_t)jq * (N * HD) + (size_t)(i0 + mg * 32 + quad * 4) * HD + colb;
    float* oB = oA + (size_t)16 * HD;
#pragma unroll
    for (int reg = 0; reg < 4; ++reg) {
      oA[(size_t)reg * HD + 0]  = accA0[reg];
      oA[(size_t)reg * HD + 16] = accA1[reg];
      oA[(size_t)reg * HD + 32] = accA2[reg];
      oA[(size_t)reg * HD + 48] = accA3[reg];
      oB[(size_t)reg * HD + 0]  = accB0[reg];
      oB[(size_t)reg * HD + 16] = accB1[reg];
      oB[(size_t)reg * HD + 32] = accB2[reg];
      oB[(size_t)reg * HD + 48] = accB3[reg];
    }
  }
}

// ---------------- K5: combine 8 partial slices ----------------
__global__ __launch_bounds__(256) void reduce_part(const float4* __restrict__ part,
                                                   float4* __restrict__ out) {
  const size_t idx = (size_t)blockIdx.x * 256 + threadIdx.x;
  const size_t S = (size_t)N * HD / 4;
  float4 o = part[idx];
#pragma unroll
  for (int k = 1; k < 8; ++k) {
    float4 a = part[idx + (size_t)k * S];
    o.x += a.x; o.y += a.y; o.z += a.z; o.w += a.w;
  }
  out[idx] = o;
}

extern "C" void kernel_launch(void* const* d_in, const int* in_sizes, int n_in,
                              void* d_out, int out_size, void* d_ws, size_t ws_size,
                              hipStream_t stream) {
  (void)in_sizes; (void)n_in;
  const float* x = (const float*)d_in[0];
  const void* mask = d_in[1];
  const float* W = (const float*)d_in[2];
  const float* a_src = (const float*)d_in[3];
  const float* a_dst = (const float*)d_in[4];
  float* out = (float*)d_out;

  char* ws = (char*)d_ws;
  _Float16* hb = (_Float16*)(ws + WS_HB_OFF);
  float* s_src = (float*)(ws + WS_SSRC_OFF);
  float* s_dst = (float*)(ws + WS_SDST_OFF);
  float* s_dst_t = (float*)(ws + WS_SDT_OFF);
  float* log2l_ws = (float*)(ws + WS_L2L_OFF);
  float* U_ws = (float*)(ws + WS_U_OFF);
  unsigned* bits = (unsigned*)(ws + WS_BITS_OFF);
  unsigned* bits_t = (unsigned*)(ws + WS_BITT_OFF);
  float* partial = (float*)(ws + WS_PART_OFF);

  pack_mask_k<<<(N * N / 32) / 256, 256, 0, stream>>>(mask, bits, bits_t);
  compute_h<<<N / 8, 256, 0, stream>>>(x, W, a_src, a_dst, hb, s_src, s_dst, s_dst_t);
  gat_scores<<<N / 4, 256, 0, stream>>>(s_src, s_dst, bits, log2l_ws, U_ws);

  if (ws_size >= (size_t)WS_NEEDED) {
    gat_aggr<<<(N / 64) * 8, 512, 0, stream>>>(hb, s_src, s_dst_t, log2l_ws, U_ws,
                                               bits_t, partial, 0);
    reduce_part<<<(N * HD / 4) / 256, 256, 0, stream>>>((const float4*)partial, (float4*)out);
  } else {
    (void)hipMemsetAsync(out, 0, (size_t)out_size * sizeof(float), stream);
    gat_aggr<<<(N / 64) * 8, 512, 0, stream>>>(hb, s_src, s_dst_t, log2l_ws, U_ws,
                                               bits_t, out, 1);
  }
}

// Round 8
// 163.520 us; speedup vs baseline: 1.3886x; 1.0638x over previous
//
#include <hip/hip_runtime.h>
#include <math.h>

// DenseGATv2Layer: N=4096, IN=128, HEADS=4, OUT_DIM=64.
// R7: R6 post-mortem — aggr fixed (frag-linear B). Profile now dominated by
// harness ws-poison fills (256MiB @ 40us) + dispatch overhead. This round:
//  (1) UNNORMALIZED aggregation: p~ = 2^(lrelu(si+sj)-8); acc = sum p~*h and
//      l = sum p~ accumulated IN the aggr loop -> gat_scores kernel DELETED.
//      reduce_part divides acc_total / l_total. Shift-8 keeps fp16 safe.
//  (2) Empty rows (l=0): reference = exact uniform 1/N -> fallback
//      hsum[col]/4096, hsum accumulated by compute_h (256-address atomics).
//  (3) pack_mask + compute_h fused into ONE heterogeneous dispatch
//      (2048 pack blocks + 512 h blocks; independent, overlap mask BW w/ VALU).
// Pipeline: memset(1KB) + prep_k + gat_aggr + reduce_part = 3 real dispatches.

#define N 4096
#define IN_DIM 128
#define HEADS 4
#define OUT_DIM 64
#define HD 256
#define LOG2E 1.4426950408889634f
#define PSHIFT 8.0f

typedef _Float16 f16x8 __attribute__((ext_vector_type(8)));
typedef __fp16 fp16x2 __attribute__((ext_vector_type(2)));
typedef float f32x4 __attribute__((ext_vector_type(4)));

union F16x8u { fp16x2 h2[4]; f16x8 v; };

// ws layout (bytes)
#define WS_HB_OFF    0u          // _Float16 hb[2048][512]      (2 MB) frag-linear
#define WS_SSRC_OFF  2097152u    // float s_src[N][4]   (scaled by log2e)
#define WS_SDT_OFF   2162688u    // float s_dst_t[4][N] (scaled)
#define WS_BITT_OFF  2228224u    // uint bits_t[64][128][64]    (2 MB)
#define WS_HSUM_OFF  4325376u    // float hsum[256]             (1 KB)
#define WS_PL_OFF    4329472u    // float partial_l[js][N][4]   (64 KB/slice)
#define WS_PART_OFF  5242880u    // float acc[js][N][256]       (4 MB/slice)
#define WS_NEED8     (5242880u + 8u * 4194304u)
#define WS_NEED2     (5242880u + 2u * 4194304u)

__device__ __forceinline__ float lrelu(float v) { return fmaxf(v, 0.2f * v); }

__device__ __forceinline__ unsigned pack_bytes(unsigned v) {
  return (v & 1u) | ((v >> 7) & 2u) | ((v >> 14) & 4u) | ((v >> 21) & 8u);
}

// ---------------- K1: fused mask-pack (blocks 0..2047) + h-compute (2048..2559) ----
__global__ __launch_bounds__(256) void prep_k(const void* __restrict__ mraw,
                                              unsigned* __restrict__ bits_t,
                                              const float* __restrict__ x,
                                              const float* __restrict__ W,
                                              const float* __restrict__ a_src,
                                              const float* __restrict__ a_dst,
                                              _Float16* __restrict__ hb,
                                              float* __restrict__ s_src,
                                              float* __restrict__ s_dst_t,
                                              float* __restrict__ hsum) {
  if (blockIdx.x < 2048) {
    // ---- mask pack: detect format from first 4KB (L2 broadcast) ----
    __shared__ int s_flag;
    if (threadIdx.x == 0) s_flag = 0;
    __syncthreads();
    const unsigned* mw = (const unsigned*)mraw;
    int bad = 0, g = 0;
    for (int i = threadIdx.x; i < 1024; i += 256) {
      unsigned v = mw[i];
      if (v & 0xFEFEFEFEu) bad = 1;
      if (v > 1u) g = 1;
    }
    if (bad || g) atomicOr(&s_flag, (bad ? 1 : 0) | (g ? 2 : 0));
    __syncthreads();
    const bool byte_fmt = ((s_flag & 1) == 0) && ((s_flag & 2) != 0);

    int w = blockIdx.x * 256 + threadIdx.x;  // word idx, N*N/32 total
    unsigned ob = 0u;
    if (byte_fmt) {
      const uint4* p = (const uint4*)((const unsigned char*)mraw + (size_t)w * 32u);
      uint4 a = p[0], b = p[1];
      ob  =  pack_bytes(a.x)        | (pack_bytes(a.y) << 4)  | (pack_bytes(a.z) << 8)  | (pack_bytes(a.w) << 12);
      ob |= (pack_bytes(b.x) << 16) | (pack_bytes(b.y) << 20) | (pack_bytes(b.z) << 24) | (pack_bytes(b.w) << 28);
    } else {
      const uint4* p = (const uint4*)((const unsigned*)mraw + (size_t)w * 32u);
#pragma unroll
      for (int k = 0; k < 8; ++k) {
        uint4 v = p[k];
        ob |= (v.x ? 1u : 0u) << (4 * k);
        ob |= (v.y ? 1u : 0u) << (4 * k + 1);
        ob |= (v.z ? 1u : 0u) << (4 * k + 2);
        ob |= (v.w ? 1u : 0u) << (4 * k + 3);
      }
    }
    const int row = w >> 7, jc = w & 127;
    bits_t[((size_t)(row >> 6) * 128 + jc) * 64 + (row & 63)] = ob;
  } else {
    // ---- h = x@W (8 rows), frag-linear fp16 store, scaled s vectors, hsum ----
    const int i0 = (blockIdx.x - 2048) * 8;
    const int c = threadIdx.x;

    float acc[8];
#pragma unroll
    for (int r = 0; r < 8; ++r) acc[r] = 0.f;

    for (int kk = 0; kk < IN_DIM / 4; ++kk) {
      const int k = kk * 4;
      float w0 = W[(size_t)(k + 0) * HD + c];
      float w1 = W[(size_t)(k + 1) * HD + c];
      float w2 = W[(size_t)(k + 2) * HD + c];
      float w3 = W[(size_t)(k + 3) * HD + c];
#pragma unroll
      for (int r = 0; r < 8; ++r) {
        float4 xv = *(const float4*)(x + (size_t)(i0 + r) * IN_DIM + k);  // uniform -> s_load
        acc[r] = fmaf(xv.x, w0, fmaf(xv.y, w1, fmaf(xv.z, w2, fmaf(xv.w, w3, acc[r]))));
      }
    }

    // frag-linear store: unit=(head, chunk=i0>>5, nt); elem(lane', t=r)
    {
      const int head = c >> 6, nt = (c >> 4) & 3, m15 = c & 15;
      const int unit = (head * 128 + (i0 >> 5)) * 4 + nt;
      const int lanep = ((i0 & 31) >> 3) * 16 + m15;
      f16x8 v;
#pragma unroll
      for (int r = 0; r < 8; ++r) v[r] = (_Float16)acc[r];
      *(f16x8*)(hb + (size_t)unit * 512 + lanep * 8) = v;
    }

    // column sums for empty-row fallback
    {
      float loc = 0.f;
#pragma unroll
      for (int r = 0; r < 8; ++r) loc += acc[r];
      atomicAdd(&hsum[c], loc);
    }

    const int hw = c >> 6, lane = c & 63;
    const float as = a_src[lane], ad = a_dst[lane];
#pragma unroll
    for (int r = 0; r < 8; ++r) {
      float vs = acc[r] * as, vd = acc[r] * ad;
#pragma unroll
      for (int off = 1; off < 64; off <<= 1) {
        vs += __shfl_xor(vs, off);
        vd += __shfl_xor(vd, off);
      }
      if (lane == 0) {
        s_src[(size_t)(i0 + r) * HEADS + hw] = vs * LOG2E;
        s_dst_t[(size_t)hw * N + (i0 + r)] = vd * LOG2E;
      }
    }
  }
}

// ---------------- K2: MFMA aggregation, unnormalized, l in-loop ----------------
// grid = 64 itiles x jsplit; 512 thr (8 waves). wave = (head, mg); rows
// rA = i0+mg*32+m15, rB = rA+16. p~ = 2^((mask? lrelu(si+sj): -1e38) - 8).
// acc slices disjoint per jq; l partials per (jq,row,head).
__global__ __launch_bounds__(512, 4) void gat_aggr(const _Float16* __restrict__ hb,
                                                   const float* __restrict__ s_src,
                                                   const float* __restrict__ s_dst_t,
                                                   const unsigned* __restrict__ bits_t,
                                                   float* __restrict__ accp,
                                                   float* __restrict__ lp,
                                                   int jshift) {
  const int jsplit = 1 << jshift;
  const int jrange = N >> jshift;
  const int chunks = jrange >> 5;
  const int tid = threadIdx.x;
  const int wave = tid >> 6;
  const int lane = tid & 63;
  const int head = wave & 3;
  const int mg = wave >> 2;
  const int m15 = lane & 15;
  const int quad = lane >> 4;
  const int jq = blockIdx.x & (jsplit - 1);
  const int it = blockIdx.x >> jshift;
  const int i0 = it * 64;
  const int rA = i0 + mg * 32 + m15;
  const int rB = rA + 16;

  const float siA = s_src[(size_t)rA * HEADS + head];
  const float siB = s_src[(size_t)rB * HEADS + head];

  const unsigned* mt = bits_t + ((size_t)it * 128 + jq * chunks) * 64 + mg * 32 + m15;
  const float* sjb = s_dst_t + (size_t)head * N + jq * jrange + quad * 8;
  const _Float16* hbp = hb + ((size_t)(head * 128 + jq * chunks) * 4) * 512 + lane * 8;

  f32x4 accA0 = {0.f, 0.f, 0.f, 0.f}, accA1 = accA0, accA2 = accA0, accA3 = accA0;
  f32x4 accB0 = accA0, accB1 = accA0, accB2 = accA0, accB3 = accA0;
  float lA = 0.f, lB = 0.f;

  const int shq = quad * 8;

  for (int c = 0; c < chunks; ++c) {
    const unsigned mwA = mt[c * 64];
    const unsigned mwB = mt[c * 64 + 16];
    const float4 sa = *(const float4*)(sjb + c * 32);
    const float4 sb = *(const float4*)(sjb + c * 32 + 4);

    const f16x8 b0 = *(const f16x8*)(hbp + (size_t)(c * 4 + 0) * 512);
    const f16x8 b1 = *(const f16x8*)(hbp + (size_t)(c * 4 + 1) * 512);
    const f16x8 b2 = *(const f16x8*)(hbp + (size_t)(c * 4 + 2) * 512);
    const f16x8 b3 = *(const f16x8*)(hbp + (size_t)(c * 4 + 3) * 512);

    const unsigned wA = mwA >> shq;
    const unsigned wB = mwB >> shq;
    const float sjs[8] = {sa.x, sa.y, sa.z, sa.w, sb.x, sb.y, sb.z, sb.w};

    F16x8u uA, uB;
#pragma unroll
    for (int t2 = 0; t2 < 4; ++t2) {
      float pA[2], pB[2];
#pragma unroll
      for (int q = 0; q < 2; ++q) {
        const int t = t2 * 2 + q;
        const float sj = sjs[t];
        float vA = lrelu(siA + sj);
        float vB = lrelu(siB + sj);
        float xA = (((wA >> t) & 1u) ? vA : -1.0e38f) - PSHIFT;
        float xB = (((wB >> t) & 1u) ? vB : -1.0e38f) - PSHIFT;
        pA[q] = __builtin_amdgcn_exp2f(xA);
        pB[q] = __builtin_amdgcn_exp2f(xB);
        lA += pA[q];
        lB += pB[q];
      }
      uA.h2[t2] = __builtin_amdgcn_cvt_pkrtz(pA[0], pA[1]);
      uB.h2[t2] = __builtin_amdgcn_cvt_pkrtz(pB[0], pB[1]);
    }

    accA0 = __builtin_amdgcn_mfma_f32_16x16x32_f16(uA.v, b0, accA0, 0, 0, 0);
    accA1 = __builtin_amdgcn_mfma_f32_16x16x32_f16(uA.v, b1, accA1, 0, 0, 0);
    accA2 = __builtin_amdgcn_mfma_f32_16x16x32_f16(uA.v, b2, accA2, 0, 0, 0);
    accA3 = __builtin_amdgcn_mfma_f32_16x16x32_f16(uA.v, b3, accA3, 0, 0, 0);
    accB0 = __builtin_amdgcn_mfma_f32_16x16x32_f16(uB.v, b0, accB0, 0, 0, 0);
    accB1 = __builtin_amdgcn_mfma_f32_16x16x32_f16(uB.v, b1, accB1, 0, 0, 0);
    accB2 = __builtin_amdgcn_mfma_f32_16x16x32_f16(uB.v, b2, accB2, 0, 0, 0);
    accB3 = __builtin_amdgcn_mfma_f32_16x16x32_f16(uB.v, b3, accB3, 0, 0, 0);
  }

  // l partials: sum the 4 quads (lanes m15, +16, +32, +48)
  lA += __shfl_xor(lA, 16); lA += __shfl_xor(lA, 32);
  lB += __shfl_xor(lB, 16); lB += __shfl_xor(lB, 32);
  if (quad == 0) {
    lp[((size_t)jq * N + rA) * HEADS + head] = lA;
    lp[((size_t)jq * N + rB) * HEADS + head] = lB;
  }

  // D layout: col = m15 (d in ntile), row = quad*4 + reg.
  const int colb = head * 64 + m15;
  float* oA = accp + (size_t)jq * (N * HD) + (size_t)(i0 + mg * 32 + quad * 4) * HD + colb;
  float* oB = oA + (size_t)16 * HD;
#pragma unroll
  for (int reg = 0; reg < 4; ++reg) {
    oA[(size_t)reg * HD + 0]  = accA0[reg];
    oA[(size_t)reg * HD + 16] = accA1[reg];
    oA[(size_t)reg * HD + 32] = accA2[reg];
    oA[(size_t)reg * HD + 48] = accA3[reg];
    oB[(size_t)reg * HD + 0]  = accB0[reg];
    oB[(size_t)reg * HD + 16] = accB1[reg];
    oB[(size_t)reg * HD + 32] = accB2[reg];
    oB[(size_t)reg * HD + 48] = accB3[reg];
  }
}

// ---------------- K3: combine slices + normalize (+ empty-row fallback) --------
__global__ __launch_bounds__(256) void reduce_part(const float4* __restrict__ accp,
                                                   const float* __restrict__ lp,
                                                   const float* __restrict__ hsum,
                                                   float4* __restrict__ out, int jsplit) {
  const size_t idx = (size_t)blockIdx.x * 256 + threadIdx.x;  // [N][64] float4s
  const int row = (int)(idx >> 6);
  const int col4 = (int)(idx & 63);
  const int head = col4 >> 4;
  const size_t S = (size_t)N * HD / 4;

  float4 o = accp[idx];
  float lt = lp[(size_t)row * HEADS + head];
  for (int k = 1; k < jsplit; ++k) {
    float4 a = accp[idx + (size_t)k * S];
    o.x += a.x; o.y += a.y; o.z += a.z; o.w += a.w;
    lt += lp[((size_t)k * N + row) * HEADS + head];
  }
  if (lt == 0.f) {
    float4 hs = ((const float4*)hsum)[col4];
    const float c = 1.0f / (float)N;
    o.x = hs.x * c; o.y = hs.y * c; o.z = hs.z * c; o.w = hs.w * c;
  } else {
    const float inv = 1.0f / lt;
    o.x *= inv; o.y *= inv; o.z *= inv; o.w *= inv;
  }
  out[idx] = o;
}

extern "C" void kernel_launch(void* const* d_in, const int* in_sizes, int n_in,
                              void* d_out, int out_size, void* d_ws, size_t ws_size,
                              hipStream_t stream) {
  (void)in_sizes; (void)n_in; (void)out_size;
  const float* x = (const float*)d_in[0];
  const void* mask = d_in[1];
  const float* W = (const float*)d_in[2];
  const float* a_src = (const float*)d_in[3];
  const float* a_dst = (const float*)d_in[4];
  float* out = (float*)d_out;

  char* ws = (char*)d_ws;
  _Float16* hb = (_Float16*)(ws + WS_HB_OFF);
  float* s_src = (float*)(ws + WS_SSRC_OFF);
  float* s_dst_t = (float*)(ws + WS_SDT_OFF);
  unsigned* bits_t = (unsigned*)(ws + WS_BITT_OFF);
  float* hsum = (float*)(ws + WS_HSUM_OFF);
  float* lp = (float*)(ws + WS_PL_OFF);
  float* accp = (float*)(ws + WS_PART_OFF);

  const int jshift = (ws_size >= (size_t)WS_NEED8) ? 3 : 1;  // 8 slices (XCD-aligned) or 2
  const int jsplit = 1 << jshift;

  (void)hipMemsetAsync(hsum, 0, HD * sizeof(float), stream);
  prep_k<<<2048 + N / 8, 256, 0, stream>>>(mask, bits_t, x, W, a_src, a_dst,
                                           hb, s_src, s_dst_t, hsum);
  gat_aggr<<<(N / 64) * jsplit, 512, 0, stream>>>(hb, s_src, s_dst_t, bits_t,
                                                  accp, lp, jshift);
  reduce_part<<<(N * HD / 4) / 256, 256, 0, stream>>>((const float4*)accp, lp, hsum,
                                                      (float4*)out, jsplit);
}

// Round 9
// 153.411 us; speedup vs baseline: 1.4801x; 1.0659x over previous
//
#include <hip/hip_runtime.h>
#include <math.h>

// DenseGATv2Layer: N=4096, IN=128, HEADS=4, OUT_DIM=64.
// R8: R7 post-mortem — prep_k 45us @ 9% VALU / 1TB/s = serialization, not BW.
// Suspects: (a) uniform s_load x-read chain in h-phase (compiler emits
// per-row s_load+waitcnt), (b) hsum atomic hotspot (512 serialized adds per
// address) at the tail. This round:
//  (1) de-fuse: pack_mask_k and compute_h separate dispatches (per-kernel
//      counters localize the 45us).
//  (2) compute_h: x staged in LDS (4KB), wave-uniform ds_read_b128 broadcasts
//      (conflict-free), no s_load chain.
//  (3) hsum via per-block plain stores hsum_part[512][256]; reduce_part sums
//      slices only in the rare empty-row branch. Memset dispatch deleted.
//  (4) aggr (unnormalized, l in-loop) + reduce unchanged from R7.

#define N 4096
#define IN_DIM 128
#define HEADS 4
#define OUT_DIM 64
#define HD 256
#define LOG2E 1.4426950408889634f
#define PSHIFT 8.0f

typedef _Float16 f16x8 __attribute__((ext_vector_type(8)));
typedef __fp16 fp16x2 __attribute__((ext_vector_type(2)));
typedef float f32x4 __attribute__((ext_vector_type(4)));

union F16x8u { fp16x2 h2[4]; f16x8 v; };

// ws layout (bytes)
#define WS_HB_OFF    0u          // _Float16 hb[2048][512]      (2 MB) frag-linear
#define WS_SSRC_OFF  2097152u    // float s_src[N][4]   (scaled by log2e)
#define WS_SDT_OFF   2162688u    // float s_dst_t[4][N] (scaled)
#define WS_BITT_OFF  2228224u    // uint bits_t[64][128][64]    (2 MB)
#define WS_HSUMP_OFF 4325376u    // float hsum_part[512][256]   (512 KB)
#define WS_PL_OFF    4849664u    // float partial_l[js][N][4]   (64 KB/slice, js<=8)
#define WS_PART_OFF  5373952u    // float acc[js][N][256]       (4 MB/slice)
#define WS_NEED8     (5373952u + 8u * 4194304u)
#define WS_NEED2     (5373952u + 2u * 4194304u)

__device__ __forceinline__ float lrelu(float v) { return fmaxf(v, 0.2f * v); }

__device__ __forceinline__ unsigned pack_bytes(unsigned v) {
  return (v & 1u) | ((v >> 7) & 2u) | ((v >> 14) & 4u) | ((v >> 21) & 8u);
}

// ---------------- K1: mask pack -> bits_t (format detect fused) ----------------
__global__ __launch_bounds__(256) void pack_mask_k(const void* __restrict__ mraw,
                                                   unsigned* __restrict__ bits_t) {
  __shared__ int s_flag;
  if (threadIdx.x == 0) s_flag = 0;
  __syncthreads();
  const unsigned* mw = (const unsigned*)mraw;
  int bad = 0, g = 0;
  for (int i = threadIdx.x; i < 1024; i += 256) {
    unsigned v = mw[i];
    if (v & 0xFEFEFEFEu) bad = 1;
    if (v > 1u) g = 1;
  }
  if (bad || g) atomicOr(&s_flag, (bad ? 1 : 0) | (g ? 2 : 0));
  __syncthreads();
  const bool byte_fmt = ((s_flag & 1) == 0) && ((s_flag & 2) != 0);

  int w = blockIdx.x * 256 + threadIdx.x;  // word idx, N*N/32 total
  unsigned ob = 0u;
  if (byte_fmt) {
    const uint4* p = (const uint4*)((const unsigned char*)mraw + (size_t)w * 32u);
    uint4 a = p[0], b = p[1];
    ob  =  pack_bytes(a.x)        | (pack_bytes(a.y) << 4)  | (pack_bytes(a.z) << 8)  | (pack_bytes(a.w) << 12);
    ob |= (pack_bytes(b.x) << 16) | (pack_bytes(b.y) << 20) | (pack_bytes(b.z) << 24) | (pack_bytes(b.w) << 28);
  } else {
    const uint4* p = (const uint4*)((const unsigned*)mraw + (size_t)w * 32u);
#pragma unroll
    for (int k = 0; k < 8; ++k) {
      uint4 v = p[k];
      ob |= (v.x ? 1u : 0u) << (4 * k);
      ob |= (v.y ? 1u : 0u) << (4 * k + 1);
      ob |= (v.z ? 1u : 0u) << (4 * k + 2);
      ob |= (v.w ? 1u : 0u) << (4 * k + 3);
    }
  }
  const int row = w >> 7, jc = w & 127;
  bits_t[((size_t)(row >> 6) * 128 + jc) * 64 + (row & 63)] = ob;
}

// ---------------- K2: h = x@W, x LDS-staged; frag-linear fp16 hb ----------------
// 512 blocks x 256 thr; block = 8 rows. x (4KB) staged via one float4/thread,
// read back as wave-uniform ds_read_b128 broadcasts (conflict-free).
__global__ __launch_bounds__(256) void compute_h(const float* __restrict__ x,
                                                 const float* __restrict__ W,
                                                 const float* __restrict__ a_src,
                                                 const float* __restrict__ a_dst,
                                                 _Float16* __restrict__ hb,
                                                 float* __restrict__ s_src,
                                                 float* __restrict__ s_dst_t,
                                                 float* __restrict__ hsum_part) {
  __shared__ float xs[8][IN_DIM];  // 4 KB
  const int i0 = blockIdx.x * 8;
  const int c = threadIdx.x;

  ((float4*)&xs[0][0])[c] = ((const float4*)(x + (size_t)i0 * IN_DIM))[c];
  __syncthreads();

  float acc[8];
#pragma unroll
  for (int r = 0; r < 8; ++r) acc[r] = 0.f;

  for (int kk = 0; kk < IN_DIM / 4; ++kk) {
    const int k = kk * 4;
    float w0 = W[(size_t)(k + 0) * HD + c];
    float w1 = W[(size_t)(k + 1) * HD + c];
    float w2 = W[(size_t)(k + 2) * HD + c];
    float w3 = W[(size_t)(k + 3) * HD + c];
#pragma unroll
    for (int r = 0; r < 8; ++r) {
      float4 xv = *(const float4*)(&xs[r][k]);  // wave-uniform -> LDS broadcast
      acc[r] = fmaf(xv.x, w0, fmaf(xv.y, w1, fmaf(xv.z, w2, fmaf(xv.w, w3, acc[r]))));
    }
  }

  // frag-linear store: unit=(head, chunk=i0>>5, nt); elem(lane', t=r)
  {
    const int head = c >> 6, nt = (c >> 4) & 3, m15 = c & 15;
    const int unit = (head * 128 + (i0 >> 5)) * 4 + nt;
    const int lanep = ((i0 & 31) >> 3) * 16 + m15;
    f16x8 v;
#pragma unroll
    for (int r = 0; r < 8; ++r) v[r] = (_Float16)acc[r];
    *(f16x8*)(hb + (size_t)unit * 512 + lanep * 8) = v;
  }

  // per-block column sums (plain store, no atomics) for empty-row fallback
  {
    float loc = 0.f;
#pragma unroll
    for (int r = 0; r < 8; ++r) loc += acc[r];
    hsum_part[(size_t)blockIdx.x * HD + c] = loc;
  }

  const int hw = c >> 6, lane = c & 63;
  const float as = a_src[lane], ad = a_dst[lane];
#pragma unroll
  for (int r = 0; r < 8; ++r) {
    float vs = acc[r] * as, vd = acc[r] * ad;
#pragma unroll
    for (int off = 1; off < 64; off <<= 1) {
      vs += __shfl_xor(vs, off);
      vd += __shfl_xor(vd, off);
    }
    if (lane == 0) {
      s_src[(size_t)(i0 + r) * HEADS + hw] = vs * LOG2E;
      s_dst_t[(size_t)hw * N + (i0 + r)] = vd * LOG2E;
    }
  }
}

// ---------------- K3: MFMA aggregation, unnormalized, l in-loop ----------------
// grid = 64 itiles x jsplit; 512 thr (8 waves). wave = (head, mg); rows
// rA = i0+mg*32+m15, rB = rA+16. p~ = 2^((mask? lrelu(si+sj): -1e38) - 8).
__global__ __launch_bounds__(512, 4) void gat_aggr(const _Float16* __restrict__ hb,
                                                   const float* __restrict__ s_src,
                                                   const float* __restrict__ s_dst_t,
                                                   const unsigned* __restrict__ bits_t,
                                                   float* __restrict__ accp,
                                                   float* __restrict__ lp,
                                                   int jshift) {
  const int jsplit = 1 << jshift;
  const int jrange = N >> jshift;
  const int chunks = jrange >> 5;
  const int tid = threadIdx.x;
  const int wave = tid >> 6;
  const int lane = tid & 63;
  const int head = wave & 3;
  const int mg = wave >> 2;
  const int m15 = lane & 15;
  const int quad = lane >> 4;
  const int jq = blockIdx.x & (jsplit - 1);
  const int it = blockIdx.x >> jshift;
  const int i0 = it * 64;
  const int rA = i0 + mg * 32 + m15;
  const int rB = rA + 16;

  const float siA = s_src[(size_t)rA * HEADS + head];
  const float siB = s_src[(size_t)rB * HEADS + head];

  const unsigned* mt = bits_t + ((size_t)it * 128 + jq * chunks) * 64 + mg * 32 + m15;
  const float* sjb = s_dst_t + (size_t)head * N + jq * jrange + quad * 8;
  const _Float16* hbp = hb + ((size_t)(head * 128 + jq * chunks) * 4) * 512 + lane * 8;

  f32x4 accA0 = {0.f, 0.f, 0.f, 0.f}, accA1 = accA0, accA2 = accA0, accA3 = accA0;
  f32x4 accB0 = accA0, accB1 = accA0, accB2 = accA0, accB3 = accA0;
  float lA = 0.f, lB = 0.f;

  const int shq = quad * 8;

  for (int c = 0; c < chunks; ++c) {
    const unsigned mwA = mt[c * 64];
    const unsigned mwB = mt[c * 64 + 16];
    const float4 sa = *(const float4*)(sjb + c * 32);
    const float4 sb = *(const float4*)(sjb + c * 32 + 4);

    const f16x8 b0 = *(const f16x8*)(hbp + (size_t)(c * 4 + 0) * 512);
    const f16x8 b1 = *(const f16x8*)(hbp + (size_t)(c * 4 + 1) * 512);
    const f16x8 b2 = *(const f16x8*)(hbp + (size_t)(c * 4 + 2) * 512);
    const f16x8 b3 = *(const f16x8*)(hbp + (size_t)(c * 4 + 3) * 512);

    const unsigned wA = mwA >> shq;
    const unsigned wB = mwB >> shq;
    const float sjs[8] = {sa.x, sa.y, sa.z, sa.w, sb.x, sb.y, sb.z, sb.w};

    F16x8u uA, uB;
#pragma unroll
    for (int t2 = 0; t2 < 4; ++t2) {
      float pA[2], pB[2];
#pragma unroll
      for (int q = 0; q < 2; ++q) {
        const int t = t2 * 2 + q;
        const float sj = sjs[t];
        float vA = lrelu(siA + sj);
        float vB = lrelu(siB + sj);
        float xA = (((wA >> t) & 1u) ? vA : -1.0e38f) - PSHIFT;
        float xB = (((wB >> t) & 1u) ? vB : -1.0e38f) - PSHIFT;
        pA[q] = __builtin_amdgcn_exp2f(xA);
        pB[q] = __builtin_amdgcn_exp2f(xB);
        lA += pA[q];
        lB += pB[q];
      }
      uA.h2[t2] = __builtin_amdgcn_cvt_pkrtz(pA[0], pA[1]);
      uB.h2[t2] = __builtin_amdgcn_cvt_pkrtz(pB[0], pB[1]);
    }

    accA0 = __builtin_amdgcn_mfma_f32_16x16x32_f16(uA.v, b0, accA0, 0, 0, 0);
    accA1 = __builtin_amdgcn_mfma_f32_16x16x32_f16(uA.v, b1, accA1, 0, 0, 0);
    accA2 = __builtin_amdgcn_mfma_f32_16x16x32_f16(uA.v, b2, accA2, 0, 0, 0);
    accA3 = __builtin_amdgcn_mfma_f32_16x16x32_f16(uA.v, b3, accA3, 0, 0, 0);
    accB0 = __builtin_amdgcn_mfma_f32_16x16x32_f16(uB.v, b0, accB0, 0, 0, 0);
    accB1 = __builtin_amdgcn_mfma_f32_16x16x32_f16(uB.v, b1, accB1, 0, 0, 0);
    accB2 = __builtin_amdgcn_mfma_f32_16x16x32_f16(uB.v, b2, accB2, 0, 0, 0);
    accB3 = __builtin_amdgcn_mfma_f32_16x16x32_f16(uB.v, b3, accB3, 0, 0, 0);
  }

  lA += __shfl_xor(lA, 16); lA += __shfl_xor(lA, 32);
  lB += __shfl_xor(lB, 16); lB += __shfl_xor(lB, 32);
  if (quad == 0) {
    lp[((size_t)jq * N + rA) * HEADS + head] = lA;
    lp[((size_t)jq * N + rB) * HEADS + head] = lB;
  }

  const int colb = head * 64 + m15;
  float* oA = accp + (size_t)jq * (N * HD) + (size_t)(i0 + mg * 32 + quad * 4) * HD + colb;
  float* oB = oA + (size_t)16 * HD;
#pragma unroll
  for (int reg = 0; reg < 4; ++reg) {
    oA[(size_t)reg * HD + 0]  = accA0[reg];
    oA[(size_t)reg * HD + 16] = accA1[reg];
    oA[(size_t)reg * HD + 32] = accA2[reg];
    oA[(size_t)reg * HD + 48] = accA3[reg];
    oB[(size_t)reg * HD + 0]  = accB0[reg];
    oB[(size_t)reg * HD + 16] = accB1[reg];
    oB[(size_t)reg * HD + 32] = accB2[reg];
    oB[(size_t)reg * HD + 48] = accB3[reg];
  }
}

// ---------------- K4: combine slices + normalize (+ rare empty-row fallback) ----
__global__ __launch_bounds__(256) void reduce_part(const float4* __restrict__ accp,
                                                   const float* __restrict__ lp,
                                                   const float* __restrict__ hsum_part,
                                                   float4* __restrict__ out, int jsplit) {
  const size_t idx = (size_t)blockIdx.x * 256 + threadIdx.x;  // [N][64] float4s
  const int row = (int)(idx >> 6);
  const int col4 = (int)(idx & 63);
  const int head = col4 >> 4;
  const size_t S = (size_t)N * HD / 4;

  float4 o = accp[idx];
  float lt = lp[(size_t)row * HEADS + head];
  for (int k = 1; k < jsplit; ++k) {
    float4 a = accp[idx + (size_t)k * S];
    o.x += a.x; o.y += a.y; o.z += a.z; o.w += a.w;
    lt += lp[((size_t)k * N + row) * HEADS + head];
  }
  if (lt == 0.f) {
    // empty row -> exact uniform 1/N: sum h over all j (512 block slices)
    float4 hs = {0.f, 0.f, 0.f, 0.f};
    for (int b = 0; b < 512; ++b) {
      float4 t = ((const float4*)hsum_part)[(size_t)b * 64 + col4];
      hs.x += t.x; hs.y += t.y; hs.z += t.z; hs.w += t.w;
    }
    const float cst = 1.0f / (float)N;
    o.x = hs.x * cst; o.y = hs.y * cst; o.z = hs.z * cst; o.w = hs.w * cst;
  } else {
    const float inv = 1.0f / lt;
    o.x *= inv; o.y *= inv; o.z *= inv; o.w *= inv;
  }
  out[idx] = o;
}

extern "C" void kernel_launch(void* const* d_in, const int* in_sizes, int n_in,
                              void* d_out, int out_size, void* d_ws, size_t ws_size,
                              hipStream_t stream) {
  (void)in_sizes; (void)n_in; (void)out_size;
  const float* x = (const float*)d_in[0];
  const void* mask = d_in[1];
  const float* W = (const float*)d_in[2];
  const float* a_src = (const float*)d_in[3];
  const float* a_dst = (const float*)d_in[4];
  float* out = (float*)d_out;

  char* ws = (char*)d_ws;
  _Float16* hb = (_Float16*)(ws + WS_HB_OFF);
  float* s_src = (float*)(ws + WS_SSRC_OFF);
  float* s_dst_t = (float*)(ws + WS_SDT_OFF);
  unsigned* bits_t = (unsigned*)(ws + WS_BITT_OFF);
  float* hsum_part = (float*)(ws + WS_HSUMP_OFF);
  float* lp = (float*)(ws + WS_PL_OFF);
  float* accp = (float*)(ws + WS_PART_OFF);

  const int jshift = (ws_size >= (size_t)WS_NEED8) ? 3 : 1;  // 8 (XCD-aligned) or 2
  const int jsplit = 1 << jshift;

  pack_mask_k<<<(N * N / 32) / 256, 256, 0, stream>>>(mask, bits_t);
  compute_h<<<N / 8, 256, 0, stream>>>(x, W, a_src, a_dst, hb, s_src, s_dst_t, hsum_part);
  gat_aggr<<<(N / 64) * jsplit, 512, 0, stream>>>(hb, s_src, s_dst_t, bits_t,
                                                  accp, lp, jshift);
  reduce_part<<<(N * HD / 4) / 256, 256, 0, stream>>>((const float4*)accp, lp, hsum_part,
                                                      (float4*)out, jsplit);
}